// Round 1
// 156.396 us; speedup vs baseline: 1.0567x; 1.0567x over previous
//
#include <hip/hip_runtime.h>
#include <math.h>

#define N_ 8192
#define D_ 512
#define NC_ 128
#define T_ 64   // 8192/128 row-tiles

typedef __attribute__((ext_vector_type(8))) short bf16x8;
typedef __attribute__((ext_vector_type(4))) float f32x4;
typedef __attribute__((ext_vector_type(4))) unsigned short us4;

static __device__ __forceinline__ unsigned short f2bf(float f) {
    union { float f; unsigned u; } c; c.f = f;
    unsigned u = c.u;
    u += 0x7fffu + ((u >> 16) & 1u);   // round-to-nearest-even
    return (unsigned short)(u >> 16);
}

// ---------- kernel 1: fp32 -> bf16 ----------
__global__ __launch_bounds__(256) void k_convert(const float* __restrict__ x,
                                                 unsigned short* __restrict__ xb) {
    int i = (blockIdx.x * 256 + threadIdx.x);
    float4 v = reinterpret_cast<const float4*>(x)[i];
    us4 o = { f2bf(v.x), f2bf(v.y), f2bf(v.z), f2bf(v.w) };
    reinterpret_cast<us4*>(xb)[i] = o;
}

// ---------- kernel 2: symmetric fused bf16 MFMA sim + masked exp partials ----
// grid = 2080 triangular tile-pairs (it<=jt), 128x128 tile, 256 threads (2x2 waves).
// 2-phase double-buffered pipeline (T3 minimum recipe): STAGE(next) issued
// BEFORE compute(cur); ONE vmcnt-draining barrier per K-step. LDS 66 KB ->
// 2 blocks/CU; load latency hides under ds_read+MFMA of the current tile.
__global__ __launch_bounds__(256, 2) void k_main(const unsigned short* __restrict__ xb,
                                                 const int* __restrict__ tg,
                                                 float* __restrict__ bufP,
                                                 float* __restrict__ bufN) {
    __shared__ alignas(16) unsigned short As[2][128 * 64];
    __shared__ alignas(16) unsigned short Bs[2][128 * 64];
    __shared__ int rowT[128];

    const int tid  = threadIdx.x;
    const int w    = tid >> 6;
    const int lane = tid & 63;
    const int q    = lane >> 4;
    const int l15  = lane & 15;
    const int wrow = w >> 1;      // 0..1
    const int wcol = w & 1;       // 0..1

    // triangular decode: blockIdx.x -> (it, jt), it<=jt
    int rem = blockIdx.x;
    int it = 0;
    while (rem >= (T_ - it)) { rem -= (T_ - it); it++; }
    const int jt = it + rem;
    const int row0 = it * 128;
    const int col0 = jt * 128;

    // stage A(128x64) and B(128x64) tile ks into buffer buf:
    // 4 wave-issues each, 16B/lane, XOR-swizzled source so LDS slot s holds
    // kgroup g = s ^ (row&7)
    auto STAGE = [&](int buf, int ks) {
        const int k0 = ks * 64;
        unsigned short* Ad = As[buf];
        unsigned short* Bd = Bs[buf];
#pragma unroll
        for (int itr = 0; itr < 4; ++itr) {
            int gs = (itr * 4 + w) * 64 + lane;
            int r  = gs >> 3;
            int s  = gs & 7;
            int g  = s ^ (r & 7);
            const unsigned short* ga = xb + (size_t)(row0 + r) * D_ + k0 + g * 8;
            const unsigned short* gb = xb + (size_t)(col0 + r) * D_ + k0 + g * 8;
            __builtin_amdgcn_global_load_lds(
                (const __attribute__((address_space(1))) void*)ga,
                (__attribute__((address_space(3))) void*)(Ad + (itr * 4 + w) * 512),
                16, 0, 0);
            __builtin_amdgcn_global_load_lds(
                (const __attribute__((address_space(1))) void*)gb,
                (__attribute__((address_space(3))) void*)(Bd + (itr * 4 + w) * 512),
                16, 0, 0);
        }
    };

    if (tid < 128) rowT[tid] = tg[row0 + tid];
    STAGE(0, 0);
    __syncthreads();   // drains vmcnt(0): buffer 0 valid, rowT visible

    int tR[4][4];
#pragma unroll
    for (int mi = 0; mi < 4; ++mi)
#pragma unroll
        for (int r = 0; r < 4; ++r)
            tR[mi][r] = rowT[wrow * 64 + mi * 16 + q * 4 + r];

    int tC[4];
#pragma unroll
    for (int ni = 0; ni < 4; ++ni)
        tC[ni] = tg[col0 + wcol * 64 + ni * 16 + l15];

    f32x4 acc[4][4];
#pragma unroll
    for (int mi = 0; mi < 4; ++mi)
#pragma unroll
        for (int ni = 0; ni < 4; ++ni)
            acc[mi][ni] = (f32x4){0.f, 0.f, 0.f, 0.f};

    auto COMPUTE = [&](int buf) {
        const unsigned short* A = As[buf];
        const unsigned short* B = Bs[buf];
#pragma unroll
        for (int kc = 0; kc < 2; ++kc) {
            bf16x8 aF[4], bF[4];
#pragma unroll
            for (int mi = 0; mi < 4; ++mi) {
                int rA = wrow * 64 + mi * 16 + l15;
                int g  = kc * 4 + q;
                int s  = g ^ (rA & 7);
                aF[mi] = *reinterpret_cast<const bf16x8*>(A + rA * 64 + s * 8);
            }
#pragma unroll
            for (int ni = 0; ni < 4; ++ni) {
                int rB = wcol * 64 + ni * 16 + l15;
                int g  = kc * 4 + q;
                int s  = g ^ (rB & 7);
                bF[ni] = *reinterpret_cast<const bf16x8*>(B + rB * 64 + s * 8);
            }
#pragma unroll
            for (int mi = 0; mi < 4; ++mi)
#pragma unroll
                for (int ni = 0; ni < 4; ++ni)
                    acc[mi][ni] = __builtin_amdgcn_mfma_f32_16x16x32_bf16(
                        aF[mi], bF[ni], acc[mi][ni], 0, 0, 0);
        }
    };

    // 2-phase pipelined K-loop: tiles 0..7 (D=512, BK=64)
    int cur = 0;
#pragma unroll 1
    for (int ks = 0; ks < 7; ++ks) {
        STAGE(cur ^ 1, ks + 1);   // next tile's loads in flight during compute
        COMPUTE(cur);
        __syncthreads();          // drains vmcnt+lgkm: next buffer valid,
                                  // prev buffer free for restage
        cur ^= 1;
    }
    COMPUTE(cur);                 // last tile (buf 1), no prefetch

    // epilogue: single exp per element; row partials and (off-diag) col partials
    float ps[4][4], ns[4][4];
    float cps[4], cns[4];
#pragma unroll
    for (int mi = 0; mi < 4; ++mi)
#pragma unroll
        for (int r = 0; r < 4; ++r) { ps[mi][r] = 0.f; ns[mi][r] = 0.f; }
#pragma unroll
    for (int ni = 0; ni < 4; ++ni) { cps[ni] = 0.f; cns[ni] = 0.f; }

#pragma unroll
    for (int mi = 0; mi < 4; ++mi)
#pragma unroll
        for (int ni = 0; ni < 4; ++ni)
#pragma unroll
            for (int r = 0; r < 4; ++r) {
                float s = acc[mi][ni][r];
                bool same = (tR[mi][r] == tC[ni]);
                float e = __expf(same ? 1.0f - s : s);
                float pe = (same && (s < 1.0f)) ? e : 0.0f;
                float ne = same ? 0.0f : e;
                ps[mi][r] += pe; ns[mi][r] += ne;
                cps[ni]   += pe; cns[ni]   += ne;
            }

    // combine wave halves through LDS (scratch = As[0], disjoint from buf 1),
    // then coalesced global stores
    __syncthreads();
    float* scr = (float*)As;         // [0:256)=rowP, [256:512)=rowN,
                                     // [512:768)=colP, [768:1024)=colN

    // row partials: sum across the 16 lanes sharing a row
#pragma unroll
    for (int mi = 0; mi < 4; ++mi)
#pragma unroll
        for (int r = 0; r < 4; ++r) {
            float p = ps[mi][r];
            float n = ns[mi][r];
#pragma unroll
            for (int m = 1; m < 16; m <<= 1) {
                p += __shfl_xor(p, m, 64);
                n += __shfl_xor(n, m, 64);
            }
            if (l15 == 0) {
                int rloc = wrow * 64 + mi * 16 + q * 4 + r;
                scr[wcol * 128 + rloc]       = p;
                scr[256 + wcol * 128 + rloc] = n;
            }
        }

    // col partials: sum across q (lane bits 16,32)
#pragma unroll
    for (int ni = 0; ni < 4; ++ni) {
        float p = cps[ni];
        float n = cns[ni];
        p += __shfl_xor(p, 16, 64); p += __shfl_xor(p, 32, 64);
        n += __shfl_xor(n, 16, 64); n += __shfl_xor(n, 32, 64);
        if (q == 0) {
            int cloc = wcol * 64 + ni * 16 + l15;
            scr[512 + wrow * 128 + cloc] = p;
            scr[768 + wrow * 128 + cloc] = n;
        }
    }
    __syncthreads();

    if (tid < 128) {
        int r = tid;
        size_t off = ((size_t)it * T_ + jt) * 128 + r;
        bufP[off] = scr[r]       + scr[128 + r];
        bufN[off] = scr[256 + r] + scr[384 + r];
    } else if (jt != it) {
        int c = tid - 128;
        size_t off = ((size_t)jt * T_ + it) * 128 + c;
        bufP[off] = scr[512 + c] + scr[640 + c];
        bufN[off] = scr[768 + c] + scr[896 + c];
    }
}

// ---------- kernel 3: exact fp64 last-row dots -> sim_last[j] ----------
__global__ __launch_bounds__(256) void k_last(const float* __restrict__ x,
                                              double* __restrict__ sim_last) {
    int j    = (blockIdx.x * 256 + threadIdx.x) >> 6;
    int lane = threadIdx.x & 63;
    const float* xl = x + (size_t)(N_ - 1) * D_;
    const float* xj = x + (size_t)j * D_;
    double acc = 0.0;
#pragma unroll
    for (int it = 0; it < 8; ++it) {
        int k = it * 64 + lane;
        acc += (double)xl[k] * (double)xj[k];
    }
#pragma unroll
    for (int m = 32; m >= 1; m >>= 1) acc += __shfl_xor(acc, m, 64);
    if (lane == 0) sim_last[j] = acc;
}

// ---------- kernel 4: reduce partials -> psum/nsum (64 blocks, coalesced) ------
__global__ __launch_bounds__(256) void k_reduce(const float* __restrict__ bufP,
                                                const float* __restrict__ bufN,
                                                float* __restrict__ psum,
                                                float* __restrict__ nsum) {
    int t    = blockIdx.x;            // tile 0..63
    int half = threadIdx.x >> 7;      // 0: psum, 1: nsum
    int r    = threadIdx.x & 127;
    const float* buf = half ? bufN : bufP;
    const float* base = buf + (size_t)t * T_ * 128 + r;
    float s = 0.f;
#pragma unroll
    for (int o = 0; o < T_; ++o) s += base[o * 128];
    if (half) nsum[t * 128 + r] = s;
    else      psum[t * 128 + r] = s;
}

// ---------- kernel 5: finalize (single block, 1024 threads) ----------
__global__ __launch_bounds__(1024) void k_final(const float* __restrict__ psum,
                                                const float* __restrict__ nsum,
                                                const int* __restrict__ tg,
                                                const double* __restrict__ sim_last,
                                                float* __restrict__ out) {
    __shared__ int lh[NC_];
    __shared__ double sl[1024], sp[1024], sn[1024];
    __shared__ int    sk[1024], cp[1024], cn[1024];
    int tid = threadIdx.x;

    if (tid < NC_) lh[tid] = 0;
    __syncthreads();
    for (int i = tid; i < N_; i += 1024) atomicAdd(&lh[tg[i]], 1);
    __syncthreads();

    // loss + prec
    double part = 0.0;
    int skip = 0;
    for (int i = tid; i < N_; i += 1024) {
        if (lh[tg[i]] < N_) {
            part += (double)(logf(psum[i]) + logf(nsum[i]));
        } else {
            skip++;
        }
    }

    // last-row stats from sim_last
    double pd = 0.0, nd = 0.0;
    int pc = 0, nc = 0;
    int tlast = tg[N_ - 1];
    for (int j = tid; j < N_; j += 1024) {
        double s = sim_last[j];
        if (tg[j] == tlast) {
            if (s < 1.0) { pd += s; pc++; }
        } else {
            nd += s; nc++;
        }
    }

    sl[tid] = part; sk[tid] = skip;
    sp[tid] = pd;   cp[tid] = pc;
    sn[tid] = nd;   cn[tid] = nc;
    __syncthreads();
    for (int s = 512; s >= 1; s >>= 1) {
        if (tid < s) {
            sl[tid] += sl[tid + s]; sk[tid] += sk[tid + s];
            sp[tid] += sp[tid + s]; cp[tid] += cp[tid + s];
            sn[tid] += sn[tid + s]; cn[tid] += cn[tid + s];
        }
        __syncthreads();
    }
    if (tid == 0) {
        out[0] = (float)(sl[0] / (double)N_);
        out[1] = (float)sk[0] / (float)N_;
        out[2] = (float)(sp[0] / (double)cp[0]);
        out[3] = (float)(sn[0] / (double)cn[0]);
    }
}

extern "C" void kernel_launch(void* const* d_in, const int* in_sizes, int n_in,
                              void* d_out, int out_size, void* d_ws, size_t ws_size,
                              hipStream_t stream) {
    const float* x  = (const float*)d_in[0];
    const int*   tg = (const int*)d_in[1];
    char* ws = (char*)d_ws;

    unsigned short* xb = (unsigned short*)ws;            // 8 MB
    const size_t XB = (size_t)N_ * D_ * 2;               // 8388608
    float*  psum     = (float*)(ws + XB);                // 32 KB
    float*  nsum     = (float*)(ws + XB + 32768);        // 32 KB
    double* sim_last = (double*)(ws + XB + 65536);       // 64 KB
    float*  bufP     = (float*)(ws + XB + 131072);       // 64*64*128*4 = 2 MB
    float*  bufN     = (float*)(ws + XB + 131072 + 2097152); // 2 MB

    const int nblk_tri = T_ * (T_ + 1) / 2;              // 2080

    hipLaunchKernelGGL(k_convert, dim3((N_ * D_) / (256 * 4)), dim3(256), 0, stream, x, xb);
    hipLaunchKernelGGL(k_main, dim3(nblk_tri), dim3(256), 0, stream, xb, tg, bufP, bufN);
    hipLaunchKernelGGL(k_last, dim3((N_ * 64) / 256), dim3(256), 0, stream, x, sim_last);
    hipLaunchKernelGGL(k_reduce, dim3(T_), dim3(256), 0, stream, bufP, bufN, psum, nsum);
    hipLaunchKernelGGL(k_final, dim3(1), dim3(1024), 0, stream,
                       psum, nsum, tg, sim_last, (float*)d_out);
}

// Round 2
// 152.824 us; speedup vs baseline: 1.0814x; 1.0234x over previous
//
#include <hip/hip_runtime.h>
#include <math.h>

#define N_ 8192
#define D_ 512
#define NC_ 128
#define T_ 64      // 8192/128 row-tiles
#define BK_ 32     // K-step
#define KSTEPS 16  // 512/32

typedef __attribute__((ext_vector_type(8))) short bf16x8;
typedef __attribute__((ext_vector_type(4))) float f32x4;
typedef __attribute__((ext_vector_type(4))) unsigned short us4;

static __device__ __forceinline__ unsigned short f2bf(float f) {
    union { float f; unsigned u; } c; c.f = f;
    unsigned u = c.u;
    u += 0x7fffu + ((u >> 16) & 1u);   // round-to-nearest-even
    return (unsigned short)(u >> 16);
}

// ---------- kernel 1: fused convert + last-row fp64 dots + class histogram ---
// blocks [0,4096): fp32 -> bf16 convert
// blocks [4096,6144): exact fp64 last-row dots -> sim_last[j]
// blocks [6144,6176): per-block class histogram slice -> hist32[b][c]
__global__ __launch_bounds__(256) void k_pre(const float* __restrict__ x,
                                             unsigned short* __restrict__ xb,
                                             const int* __restrict__ tg,
                                             double* __restrict__ sim_last,
                                             int* __restrict__ hist32) {
    const int bid = blockIdx.x;
    const int tid = threadIdx.x;
    if (bid < 4096) {
        int i = bid * 256 + tid;
        float4 v = reinterpret_cast<const float4*>(x)[i];
        us4 o = { f2bf(v.x), f2bf(v.y), f2bf(v.z), f2bf(v.w) };
        reinterpret_cast<us4*>(xb)[i] = o;
    } else if (bid < 6144) {
        int j    = (bid - 4096) * 4 + (tid >> 6);
        int lane = tid & 63;
        const float* xl = x + (size_t)(N_ - 1) * D_;
        const float* xj = x + (size_t)j * D_;
        double acc = 0.0;
#pragma unroll
        for (int it = 0; it < 8; ++it) {
            int k = it * 64 + lane;
            acc += (double)xl[k] * (double)xj[k];
        }
#pragma unroll
        for (int m = 32; m >= 1; m >>= 1) acc += __shfl_xor(acc, m, 64);
        if (lane == 0) sim_last[j] = acc;
    } else {
        __shared__ int lh[NC_];
        int b = bid - 6144;                 // 0..31
        if (tid < NC_) lh[tid] = 0;
        __syncthreads();
        atomicAdd(&lh[tg[b * 256 + tid]], 1);
        __syncthreads();
        if (tid < NC_) hist32[b * NC_ + tid] = lh[tid];
    }
}

// ---------- kernel 2: symmetric fused bf16 MFMA sim + masked exp partials ----
// grid = 2080 triangular tile-pairs (it<=jt), 128x128 tile, 256 threads (2x2 waves).
// 2-phase double-buffered pipeline, BK=32: LDS 33 KB -> 4 blocks/CU (16 waves),
// so barrier stalls of one block overlap other blocks' MFMA (TLP latency hiding).
// XCD-chunked blockIdx swizzle: 2080%8==0, each XCD gets 260 consecutive
// triangular ids (mostly same it) -> A-panel L2 locality.
__global__ __launch_bounds__(256, 4) void k_main(const unsigned short* __restrict__ xb,
                                                 const int* __restrict__ tg,
                                                 float* __restrict__ bufP,
                                                 float* __restrict__ bufN) {
    __shared__ alignas(16) unsigned short As[2][128 * BK_];
    __shared__ alignas(16) unsigned short Bs[2][128 * BK_];
    __shared__ int rowT[128];

    const int tid  = threadIdx.x;
    const int w    = tid >> 6;
    const int lane = tid & 63;
    const int q    = lane >> 4;
    const int l15  = lane & 15;
    const int wrow = w >> 1;      // 0..1
    const int wcol = w & 1;       // 0..1

    // XCD-chunked bijective swizzle (nblk=2080, 2080/8=260)
    const int bswz = (blockIdx.x & 7) * 260 + (blockIdx.x >> 3);

    // triangular decode: bswz -> (it, jt), it<=jt
    int rem = bswz;
    int it = 0;
    while (rem >= (T_ - it)) { rem -= (T_ - it); it++; }
    const int jt = it + rem;
    const int row0 = it * 128;
    const int col0 = jt * 128;

    // stage A(128x32) and B(128x32) of K-tile ks into buffer buf.
    // XOR-swizzled source: LDS slot s (of 4 per row) holds kgroup g = s ^ ((r>>1)&3)
    // -> ds_read_b128 lands 2 lanes/bank (free) per 16-lane group.
    auto STAGE = [&](int buf, int ks) {
        const int k0 = ks * BK_;
        unsigned short* Ad = As[buf];
        unsigned short* Bd = Bs[buf];
#pragma unroll
        for (int itr = 0; itr < 2; ++itr) {
            int slot = itr * 4 + w;          // 0..7
            int gs = slot * 64 + lane;       // 0..511 16B-chunks
            int r  = gs >> 2;
            int sl = gs & 3;
            int g  = sl ^ ((r >> 1) & 3);
            const unsigned short* ga = xb + (size_t)(row0 + r) * D_ + k0 + g * 8;
            const unsigned short* gb = xb + (size_t)(col0 + r) * D_ + k0 + g * 8;
            __builtin_amdgcn_global_load_lds(
                (const __attribute__((address_space(1))) void*)ga,
                (__attribute__((address_space(3))) void*)(Ad + slot * 512),
                16, 0, 0);
            __builtin_amdgcn_global_load_lds(
                (const __attribute__((address_space(1))) void*)gb,
                (__attribute__((address_space(3))) void*)(Bd + slot * 512),
                16, 0, 0);
        }
    };

    if (tid < 128) rowT[tid] = tg[row0 + tid];
    STAGE(0, 0);
    __syncthreads();   // drains vmcnt(0): buffer 0 valid, rowT visible

    int tR[4][4];
#pragma unroll
    for (int mi = 0; mi < 4; ++mi)
#pragma unroll
        for (int r = 0; r < 4; ++r)
            tR[mi][r] = rowT[wrow * 64 + mi * 16 + q * 4 + r];

    int tC[4];
#pragma unroll
    for (int ni = 0; ni < 4; ++ni)
        tC[ni] = tg[col0 + wcol * 64 + ni * 16 + l15];

    f32x4 acc[4][4];
#pragma unroll
    for (int mi = 0; mi < 4; ++mi)
#pragma unroll
        for (int ni = 0; ni < 4; ++ni)
            acc[mi][ni] = (f32x4){0.f, 0.f, 0.f, 0.f};

    auto COMPUTE = [&](int buf) {
        const unsigned short* A = As[buf];
        const unsigned short* B = Bs[buf];
        bf16x8 aF[4], bF[4];
#pragma unroll
        for (int mi = 0; mi < 4; ++mi) {
            int rA = wrow * 64 + mi * 16 + l15;
            int sl = q ^ ((rA >> 1) & 3);
            aF[mi] = *reinterpret_cast<const bf16x8*>(A + rA * BK_ + sl * 8);
        }
#pragma unroll
        for (int ni = 0; ni < 4; ++ni) {
            int rB = wcol * 64 + ni * 16 + l15;
            int sl = q ^ ((rB >> 1) & 3);
            bF[ni] = *reinterpret_cast<const bf16x8*>(B + rB * BK_ + sl * 8);
        }
#pragma unroll
        for (int mi = 0; mi < 4; ++mi)
#pragma unroll
            for (int ni = 0; ni < 4; ++ni)
                acc[mi][ni] = __builtin_amdgcn_mfma_f32_16x16x32_bf16(
                    aF[mi], bF[ni], acc[mi][ni], 0, 0, 0);
    };

    // 2-phase pipelined K-loop: tiles 0..15
    int cur = 0;
#pragma unroll 1
    for (int ks = 0; ks < KSTEPS - 1; ++ks) {
        STAGE(cur ^ 1, ks + 1);   // next tile's loads in flight during compute
        COMPUTE(cur);
        __syncthreads();          // next buffer valid, prev buffer free
        cur ^= 1;
    }
    COMPUTE(cur);                 // last tile, no prefetch

    // epilogue: single exp per element; row partials and (off-diag) col partials
    float ps[4][4], ns[4][4];
    float cps[4], cns[4];
#pragma unroll
    for (int mi = 0; mi < 4; ++mi)
#pragma unroll
        for (int r = 0; r < 4; ++r) { ps[mi][r] = 0.f; ns[mi][r] = 0.f; }
#pragma unroll
    for (int ni = 0; ni < 4; ++ni) { cps[ni] = 0.f; cns[ni] = 0.f; }

#pragma unroll
    for (int mi = 0; mi < 4; ++mi)
#pragma unroll
        for (int ni = 0; ni < 4; ++ni)
#pragma unroll
            for (int r = 0; r < 4; ++r) {
                float s = acc[mi][ni][r];
                bool same = (tR[mi][r] == tC[ni]);
                float e = __expf(same ? 1.0f - s : s);
                float pe = (same && (s < 1.0f)) ? e : 0.0f;
                float ne = same ? 0.0f : e;
                ps[mi][r] += pe; ns[mi][r] += ne;
                cps[ni]   += pe; cns[ni]   += ne;
            }

    // combine wave halves through LDS (scratch = As[0], last compute used buf 1)
    __syncthreads();
    float* scr = (float*)As;         // [0:256)=rowP, [256:512)=rowN,
                                     // [512:768)=colP, [768:1024)=colN

    // row partials: sum across the 16 lanes sharing a row
#pragma unroll
    for (int mi = 0; mi < 4; ++mi)
#pragma unroll
        for (int r = 0; r < 4; ++r) {
            float p = ps[mi][r];
            float n = ns[mi][r];
#pragma unroll
            for (int m = 1; m < 16; m <<= 1) {
                p += __shfl_xor(p, m, 64);
                n += __shfl_xor(n, m, 64);
            }
            if (l15 == 0) {
                int rloc = wrow * 64 + mi * 16 + q * 4 + r;
                scr[wcol * 128 + rloc]       = p;
                scr[256 + wcol * 128 + rloc] = n;
            }
        }

    // col partials: sum across q (lane bits 16,32)
#pragma unroll
    for (int ni = 0; ni < 4; ++ni) {
        float p = cps[ni];
        float n = cns[ni];
        p += __shfl_xor(p, 16, 64); p += __shfl_xor(p, 32, 64);
        n += __shfl_xor(n, 16, 64); n += __shfl_xor(n, 32, 64);
        if (q == 0) {
            int cloc = wcol * 64 + ni * 16 + l15;
            scr[512 + wrow * 128 + cloc] = p;
            scr[768 + wrow * 128 + cloc] = n;
        }
    }
    __syncthreads();

    if (tid < 128) {
        int r = tid;
        size_t off = ((size_t)it * T_ + jt) * 128 + r;
        bufP[off] = scr[r]       + scr[128 + r];
        bufN[off] = scr[256 + r] + scr[384 + r];
    } else if (jt != it) {
        int c = tid - 128;
        size_t off = ((size_t)jt * T_ + it) * 128 + c;
        bufP[off] = scr[512 + c] + scr[640 + c];
        bufN[off] = scr[768 + c] + scr[896 + c];
    }
}

// ---------- kernel 3: reduce partials -> per-tile loss partial (64 blocks) ----
// Also applies the per-row log and skip test (moved off the single-block k_final).
__global__ __launch_bounds__(256) void k_reduce(const float* __restrict__ bufP,
                                                const float* __restrict__ bufN,
                                                const int* __restrict__ tg,
                                                const int* __restrict__ hist32,
                                                double* __restrict__ partd,
                                                int* __restrict__ skipc) {
    __shared__ float sv[256];
    __shared__ int lh[NC_];
    __shared__ double rd[128];
    __shared__ int ri[128];
    const int t   = blockIdx.x;       // tile 0..63
    const int tid = threadIdx.x;
    const int half = tid >> 7;        // 0: psum, 1: nsum
    const int r    = tid & 127;
    const float* buf = half ? bufN : bufP;
    const float* base = buf + (size_t)t * T_ * 128 + r;
    float s = 0.f;
#pragma unroll
    for (int o = 0; o < T_; ++o) s += base[o * 128];
    sv[tid] = s;
    if (tid < NC_) {
        int a = 0;
#pragma unroll
        for (int b = 0; b < 32; ++b) a += hist32[b * NC_ + tid];
        lh[tid] = a;
    }
    __syncthreads();
    if (tid < 128) {
        int row = t * 128 + tid;
        bool ok = lh[tg[row]] < N_;
        rd[tid] = ok ? (double)(logf(sv[tid]) + logf(sv[128 + tid])) : 0.0;
        ri[tid] = ok ? 0 : 1;
    }
    __syncthreads();
    for (int st = 64; st >= 1; st >>= 1) {
        if (tid < st) { rd[tid] += rd[tid + st]; ri[tid] += ri[tid + st]; }
        __syncthreads();
    }
    if (tid == 0) { partd[t] = rd[0]; skipc[t] = ri[0]; }
}

// ---------- kernel 4: finalize (single block, 1024 threads, light) ----------
__global__ __launch_bounds__(1024) void k_final(const double* __restrict__ partd,
                                                const int* __restrict__ skipc,
                                                const int* __restrict__ tg,
                                                const double* __restrict__ sim_last,
                                                float* __restrict__ out) {
    __shared__ double sl[1024], sp[1024], sn[1024];
    __shared__ int    sk[1024], cp[1024], cn[1024];
    int tid = threadIdx.x;

    double part = (tid < 64) ? partd[tid] : 0.0;
    int    skip = (tid < 64) ? skipc[tid] : 0;

    // last-row stats from sim_last
    double pd = 0.0, nd = 0.0;
    int pc = 0, nc = 0;
    int tlast = tg[N_ - 1];
    for (int j = tid; j < N_; j += 1024) {
        double s = sim_last[j];
        if (tg[j] == tlast) {
            if (s < 1.0) { pd += s; pc++; }
        } else {
            nd += s; nc++;
        }
    }

    sl[tid] = part; sk[tid] = skip;
    sp[tid] = pd;   cp[tid] = pc;
    sn[tid] = nd;   cn[tid] = nc;
    __syncthreads();
    for (int s = 512; s >= 1; s >>= 1) {
        if (tid < s) {
            sl[tid] += sl[tid + s]; sk[tid] += sk[tid + s];
            sp[tid] += sp[tid + s]; cp[tid] += cp[tid + s];
            sn[tid] += sn[tid + s]; cn[tid] += cn[tid + s];
        }
        __syncthreads();
    }
    if (tid == 0) {
        out[0] = (float)(sl[0] / (double)N_);
        out[1] = (float)sk[0] / (float)N_;
        out[2] = (float)(sp[0] / (double)cp[0]);
        out[3] = (float)(sn[0] / (double)cn[0]);
    }
}

extern "C" void kernel_launch(void* const* d_in, const int* in_sizes, int n_in,
                              void* d_out, int out_size, void* d_ws, size_t ws_size,
                              hipStream_t stream) {
    const float* x  = (const float*)d_in[0];
    const int*   tg = (const int*)d_in[1];
    char* ws = (char*)d_ws;

    unsigned short* xb = (unsigned short*)ws;            // 8 MB
    const size_t XB = (size_t)N_ * D_ * 2;               // 8388608
    double* partd    = (double*)(ws + XB);               // 512 B
    int*    skipc    = (int*)(ws + XB + 512);            // 256 B
    int*    hist32   = (int*)(ws + XB + 1024);           // 16 KB
    double* sim_last = (double*)(ws + XB + 65536);       // 64 KB
    float*  bufP     = (float*)(ws + XB + 131072);       // 2 MB
    float*  bufN     = (float*)(ws + XB + 131072 + 2097152); // 2 MB

    const int nblk_tri = T_ * (T_ + 1) / 2;              // 2080

    hipLaunchKernelGGL(k_pre, dim3(4096 + 2048 + 32), dim3(256), 0, stream,
                       x, xb, tg, sim_last, hist32);
    hipLaunchKernelGGL(k_main, dim3(nblk_tri), dim3(256), 0, stream, xb, tg, bufP, bufN);
    hipLaunchKernelGGL(k_reduce, dim3(T_), dim3(256), 0, stream,
                       bufP, bufN, tg, hist32, partd, skipc);
    hipLaunchKernelGGL(k_final, dim3(1), dim3(1024), 0, stream,
                       partd, skipc, tg, sim_last, (float*)d_out);
}